// Round 5
// baseline (2143.196 us; speedup 1.0000x reference)
//
#include <hip/hip_runtime.h>
#include <hip/hip_fp16.h>
#include <math.h>

#define N_NODES 30000
#define E_EDGES 480000
#define VD      512
#define HID     32
#define NBLK    1024
#define NTHR    256
#define GSTRIDE (NBLK * NTHR)
#define MAGIC   0x13579BDF

// ws float-index layout (4-byte elements):
//   [0, 16)            sync: [0]=flag, [1..4]=barrier counters
//   [16, 30016)        sarr    (float)
//   [30016, 35136)     part    (float, NBLK x 5 moment partials)
//   [35136, 65136)     counts  (int, zeroed in A0, hist in A1; read in D)
//   [65152, 95152)     cursors (int, scan in A2; bumped to row-end in A3)
//   [95168, 575168)    srcs    (int, CSR-sorted src ids)
//   fp32 path: [575168, 605168) inv
//   fp16 path: byte 2301952+    nvis (fp16 normalized rows, 1024 B/row)
#define SARR_OFF 16
#define PART_OFF 30016
#define CNT_OFF  35136
#define CURS_OFF 65152
#define SRCS_OFF 95168
#define INV_OFF  575168
#define NV_BYTE_OFF 2301952u

__device__ inline float2 h2f(unsigned int u) {
    const __half2 h = *reinterpret_cast<const __half2*>(&u);
    return __half22float2(h);
}

__device__ __forceinline__ void grid_barrier(int* ctr, int nb) {
    __syncthreads();
    if (threadIdx.x == 0) {
        __threadfence();  // publish this block's prior writes device-wide
        __hip_atomic_fetch_add(ctr, 1, __ATOMIC_ACQ_REL, __HIP_MEMORY_SCOPE_AGENT);
        while (__hip_atomic_load(ctr, __ATOMIC_ACQUIRE, __HIP_MEMORY_SCOPE_AGENT) < nb) {
            __builtin_amdgcn_s_sleep(1);
        }
    }
    __syncthreads();
}

__global__ void __launch_bounds__(NTHR, 4) k_all(
        const float* __restrict__ x,
        const float* __restrict__ visual,
        const int* __restrict__ ei,
        const float* __restrict__ w1, const float* __restrict__ b1,
        const float* __restrict__ gamma, const float* __restrict__ beta,
        const float* __restrict__ prelu_a,
        const float* __restrict__ w2, const float* __restrict__ b2,
        const float* __restrict__ wc, const float* __restrict__ bc,
        const float* __restrict__ wp, const float* __restrict__ bp,
        float* __restrict__ out, float* __restrict__ ws, int fp16mode) {
    int* sync    = (int*)ws;
    float* sarr  = ws + SARR_OFF;
    float* part  = ws + PART_OFF;
    int* counts  = (int*)(ws + CNT_OFF);
    int* cursors = (int*)(ws + CURS_OFF);
    int* srcs    = (int*)(ws + SRCS_OFF);
    float* inv   = ws + INV_OFF;
    ushort* nvis = (ushort*)((char*)ws + NV_BYTE_OFF);

    const int t      = threadIdx.x;
    const int gid    = blockIdx.x * NTHR + t;
    const int lane   = t & 63;
    const int wave   = gid >> 6;
    const int nwave  = GSTRIDE >> 6;

    // ---- init handshake: ws is poisoned; block 0 zeroes barrier counters ----
    if (blockIdx.x == 0 && t == 0) {
        __hip_atomic_store(&sync[1], 0, __ATOMIC_RELAXED, __HIP_MEMORY_SCOPE_AGENT);
        __hip_atomic_store(&sync[2], 0, __ATOMIC_RELAXED, __HIP_MEMORY_SCOPE_AGENT);
        __hip_atomic_store(&sync[3], 0, __ATOMIC_RELAXED, __HIP_MEMORY_SCOPE_AGENT);
        __hip_atomic_store(&sync[4], 0, __ATOMIC_RELAXED, __HIP_MEMORY_SCOPE_AGENT);
        __hip_atomic_store(&sync[0], MAGIC, __ATOMIC_RELEASE, __HIP_MEMORY_SCOPE_AGENT);
    }
    if (t == 0) {
        while (__hip_atomic_load(&sync[0], __ATOMIC_ACQUIRE, __HIP_MEMORY_SCOPE_AGENT) != MAGIC) {
            __builtin_amdgcn_s_sleep(1);
        }
    }
    __syncthreads();

    // ================= A0: zero counts + x-moments + normalize rows =================
    for (int i = gid; i < N_NODES; i += GSTRIDE) counts[i] = 0;

    {
        __shared__ float red[4][5];
        float s0 = 0.f, s1 = 0.f, s00 = 0.f, s11 = 0.f, s01 = 0.f;
        for (int i = gid; i < N_NODES; i += GSTRIDE) {
            float2 v = ((const float2*)x)[i];
            s0  += v.x;       s1  += v.y;
            s00 += v.x * v.x; s11 += v.y * v.y;
            s01 += v.x * v.y;
        }
        for (int o = 32; o; o >>= 1) {
            s0  += __shfl_xor(s0,  o, 64);
            s1  += __shfl_xor(s1,  o, 64);
            s00 += __shfl_xor(s00, o, 64);
            s11 += __shfl_xor(s11, o, 64);
            s01 += __shfl_xor(s01, o, 64);
        }
        int wv = t >> 6;
        if (lane == 0) {
            red[wv][0] = s0; red[wv][1] = s1; red[wv][2] = s00;
            red[wv][3] = s11; red[wv][4] = s01;
        }
        __syncthreads();
        if (t < 5) {
            part[blockIdx.x * 5 + t] = red[0][t] + red[1][t] + red[2][t] + red[3][t];
        }
    }

    for (int node = wave; node < N_NODES; node += nwave) {
        const float4* row = (const float4*)(visual + (size_t)node * VD);
        float4 a = row[lane];
        float4 b = row[lane + 64];
        float p = a.x*a.x + a.y*a.y + a.z*a.z + a.w*a.w
                + b.x*b.x + b.y*b.y + b.z*b.z + b.w*b.w;
        for (int o = 32; o; o >>= 1) p += __shfl_xor(p, o, 64);
        float r = 1.0f / fmaxf(sqrtf(p), 1e-8f);
        if (fp16mode) {
            __half2 p0 = __floats2half2_rn(a.x * r, a.y * r);
            __half2 p1 = __floats2half2_rn(a.z * r, a.w * r);
            __half2 p2 = __floats2half2_rn(b.x * r, b.y * r);
            __half2 p3 = __floats2half2_rn(b.z * r, b.w * r);
            uint2 q0, q1;
            q0.x = *(unsigned int*)&p0; q0.y = *(unsigned int*)&p1;
            q1.x = *(unsigned int*)&p2; q1.y = *(unsigned int*)&p3;
            uint2* orow = (uint2*)(nvis + (size_t)node * VD);
            orow[lane]      = q0;
            orow[lane + 64] = q1;
        } else if (lane == 0) {
            inv[node] = r;
        }
    }

    grid_barrier(&sync[1], NBLK);

    // ================= A1: dst histogram + per-node scalar sarr =================
    for (int e = gid; e < E_EDGES; e += GSTRIDE)
        atomicAdd(&counts[ei[E_EDGES + e]], 1);

    {
        __shared__ float s_scale[HID], s_shift[HID], s_u[HID], s_w1a[HID], s_w1b[HID];
        __shared__ float s_wpc[HID];
        __shared__ float s_sb;
        if (t < HID) {
            float S0 = 0, S1 = 0, S00 = 0, S11 = 0, S01 = 0;
            for (int p = 0; p < NBLK; ++p) {
                S0  += part[p * 5 + 0];
                S1  += part[p * 5 + 1];
                S00 += part[p * 5 + 2];
                S11 += part[p * 5 + 3];
                S01 += part[p * 5 + 4];
            }
            float wpck = 0.f;
            for (int j = 0; j < HID; ++j) wpck += wp[j] * wc[j * HID + t];
            s_wpc[t] = wpck;
            const float invN = 1.0f / (float)N_NODES;
            float m0  = S0 * invN, m1 = S1 * invN;
            float v0  = fmaxf(S00 * invN - m0 * m0, 0.f);
            float v1  = fmaxf(S11 * invN - m1 * m1, 0.f);
            float c01 = S01 * invN - m0 * m1;
            float a0 = w1[2 * t], a1 = w1[2 * t + 1];
            float mean = a0 * m0 + a1 * m1 + b1[t];
            float var  = fmaxf(a0 * a0 * v0 + a1 * a1 * v1 + 2.f * a0 * a1 * c01, 0.f);
            float rs    = 1.0f / sqrtf(var + 1e-5f);
            float scale = gamma[t] * rs;
            s_scale[t] = scale;
            s_shift[t] = beta[t] - mean * scale;
            s_w1a[t] = a0; s_w1b[t] = a1;
        }
        __syncthreads();
        if (t < HID) {
            float uu = 0.f;
            for (int k = 0; k < HID; ++k) uu += s_wpc[k] * w2[k * HID + t];
            s_u[t] = uu;
        }
        if (t == 0) {
            float sb = 0.f;
            for (int k = 0; k < HID; ++k) sb += s_wpc[k] * b2[k];
            s_sb = sb;
        }
        __syncthreads();
        const float aslope = prelu_a[0];
        const float sb = s_sb;
        for (int i = gid; i < N_NODES; i += GSTRIDE) {
            float2 xv = ((const float2*)x)[i];
            float sacc = sb;
            #pragma unroll
            for (int c = 0; c < HID; ++c) {
                float h  = s_w1a[c] * xv.x + s_w1b[c] * xv.y + b1[c];
                float tt = h * s_scale[c] + s_shift[c];
                tt = tt >= 0.f ? tt : aslope * tt;
                sacc += tt * s_u[c];
            }
            sarr[i] = sacc;
        }
    }

    grid_barrier(&sync[2], NBLK);

    // ================= A2: block 0 exclusive-scans counts -> cursors =================
    if (blockIdx.x == 0) {
        __shared__ int ssum[NTHR];
        const int chunk = (N_NODES + NTHR - 1) / NTHR;  // 118
        int b = t * chunk;
        int e = min(b + chunk, N_NODES);
        int s = 0;
        for (int i = b; i < e; ++i) s += counts[i];
        ssum[t] = s;
        __syncthreads();
        for (int off = 1; off < NTHR; off <<= 1) {
            int v = (t >= off) ? ssum[t - off] : 0;
            __syncthreads();
            ssum[t] += v;
            __syncthreads();
        }
        int run = ssum[t] - s;  // exclusive base of this chunk
        for (int i = b; i < e; ++i) {
            cursors[i] = run;
            run += counts[i];
        }
    }

    grid_barrier(&sync[3], NBLK);

    // ================= A3: scatter src ids into CSR order =================
    for (int e = gid; e < E_EDGES; e += GSTRIDE) {
        int s = ei[e];
        int d = ei[E_EDGES + e];
        int pos = atomicAdd(&cursors[d], 1);
        srcs[pos] = s;
    }

    grid_barrier(&sync[4], NBLK);

    // ================= D: wave per dst — acc = sum s_e * n_src; out = dot(n_dst,acc)/deg + K
    float K = bp[0];
    #pragma unroll
    for (int j = 0; j < HID; ++j) K += wp[j] * bc[j];

    if (fp16mode) {
        const uint4* nv4 = (const uint4*)nvis;
        for (int d = wave; d < N_NODES; d += nwave) {
            int cnt_d = counts[d];
            int end   = cursors[d];        // after scatter: row end
            int beg   = end - cnt_d;
            uint4 D = nv4[(size_t)d * 64 + lane];
            float2 d0 = h2f(D.x), d1 = h2f(D.y), d2 = h2f(D.z), d3 = h2f(D.w);
            float acc0 = 0.f, acc1 = 0.f, acc2 = 0.f, acc3 = 0.f;
            float acc4 = 0.f, acc5 = 0.f, acc6 = 0.f, acc7 = 0.f;
            for (int base = beg; base < end; base += 64) {
                int cnt = min(64, end - base);
                int   myidx = (lane < cnt) ? srcs[base + lane] : 0;
                float mys   = (lane < cnt) ? sarr[myidx] : 0.f;
                for (int j = 0; j < cnt; ++j) {
                    int   s  = __shfl(myidx, j, 64);
                    float sv = __shfl(mys,   j, 64);
                    uint4 A = nv4[(size_t)s * 64 + lane];
                    float2 a0 = h2f(A.x), a1 = h2f(A.y), a2 = h2f(A.z), a3 = h2f(A.w);
                    acc0 += sv * a0.x; acc1 += sv * a0.y;
                    acc2 += sv * a1.x; acc3 += sv * a1.y;
                    acc4 += sv * a2.x; acc5 += sv * a2.y;
                    acc6 += sv * a3.x; acc7 += sv * a3.y;
                }
            }
            float p = acc0 * d0.x + acc1 * d0.y + acc2 * d1.x + acc3 * d1.y
                    + acc4 * d2.x + acc5 * d2.y + acc6 * d3.x + acc7 * d3.y;
            for (int o = 32; o; o >>= 1) p += __shfl_xor(p, o, 64);
            if (lane == 0)
                out[d] = p / fmaxf((float)cnt_d, 1.0f) + K;
        }
    } else {
        for (int d = wave; d < N_NODES; d += nwave) {
            int cnt_d = counts[d];
            int end   = cursors[d];
            int beg   = end - cnt_d;
            const float4* drow = (const float4*)(visual + (size_t)d * VD);
            float4 D0 = drow[lane];
            float4 D1 = drow[lane + 64];
            float acc[8] = {0.f};
            for (int base = beg; base < end; base += 64) {
                int cnt = min(64, end - base);
                int   myidx = (lane < cnt) ? srcs[base + lane] : 0;
                float mys   = (lane < cnt) ? sarr[myidx] * inv[myidx] : 0.f;
                for (int j = 0; j < cnt; ++j) {
                    int   s  = __shfl(myidx, j, 64);
                    float sv = __shfl(mys,   j, 64);
                    const float4* srow = (const float4*)(visual + (size_t)s * VD);
                    float4 A0 = srow[lane];
                    float4 A1 = srow[lane + 64];
                    acc[0] += sv * A0.x; acc[1] += sv * A0.y;
                    acc[2] += sv * A0.z; acc[3] += sv * A0.w;
                    acc[4] += sv * A1.x; acc[5] += sv * A1.y;
                    acc[6] += sv * A1.z; acc[7] += sv * A1.w;
                }
            }
            float p = acc[0] * D0.x + acc[1] * D0.y + acc[2] * D0.z + acc[3] * D0.w
                    + acc[4] * D1.x + acc[5] * D1.y + acc[6] * D1.z + acc[7] * D1.w;
            for (int o = 32; o; o >>= 1) p += __shfl_xor(p, o, 64);
            if (lane == 0)
                out[d] = p * inv[d] / fmaxf((float)cnt_d, 1.0f) + K;
        }
    }
}

extern "C" void kernel_launch(void* const* d_in, const int* in_sizes, int n_in,
                              void* d_out, int out_size, void* d_ws, size_t ws_size,
                              hipStream_t stream) {
    const float* x       = (const float*)d_in[0];
    const float* visual  = (const float*)d_in[1];
    const int*   ei      = (const int*)  d_in[2];
    const float* w1      = (const float*)d_in[3];
    const float* b1      = (const float*)d_in[4];
    const float* gamma   = (const float*)d_in[5];
    const float* beta    = (const float*)d_in[6];
    const float* prelu_a = (const float*)d_in[7];
    const float* w2      = (const float*)d_in[8];
    const float* b2      = (const float*)d_in[9];
    const float* wc      = (const float*)d_in[10];
    const float* bc      = (const float*)d_in[11];
    const float* wp      = (const float*)d_in[12];
    const float* bp      = (const float*)d_in[13];
    float* out = (float*)d_out;
    float* ws  = (float*)d_ws;

    bool fp16ok = ws_size >= (size_t)NV_BYTE_OFF + (size_t)N_NODES * VD * 2;

    k_all<<<NBLK, NTHR, 0, stream>>>(x, visual, ei, w1, b1, gamma, beta, prelu_a,
                                     w2, b2, wc, bc, wp, bp, out, ws,
                                     fp16ok ? 1 : 0);
}

// Round 6
// 332.378 us; speedup vs baseline: 6.4481x; 6.4481x over previous
//
#include <hip/hip_runtime.h>
#include <hip/hip_fp16.h>
#include <math.h>

#define N_NODES 30000
#define E_EDGES 480000
#define VD      512
#define HID     32

// ws layout (float index):
//   [0, 30000)      acc   (float, zeroed by k1)
//   [30000, 60000)  deg   (float, zeroed by k1)
//   [60000, 90000)  sarr  (float, written by k1)
//   [90000, 120000) inv   (float, fp32 fallback only)
//   byte 360448+    nvis  (fp16 normalized rows, 1024 B/row, written by k1)
#define ACC_OFF  0
#define DEG_OFF  30000
#define SARR_OFF 60000
#define INV_OFF  90000
#define NV_BYTE_OFF 360448u

__device__ inline float2 h2f(unsigned int u) {
    const __half2 h = *reinterpret_cast<const __half2*>(&u);
    return __half22float2(h);
}

// ================= K1: all node-side work, no cross-block deps =================
// Every block redundantly computes the x-moments (240 KB, L2-cached) so the
// BN scalars are available block-locally — removes the stats->sarr dispatch dep.
__global__ void __launch_bounds__(256) k1_node(
        const float* __restrict__ x,
        const float* __restrict__ visual,
        const float* __restrict__ w1, const float* __restrict__ b1,
        const float* __restrict__ gamma, const float* __restrict__ beta,
        const float* __restrict__ prelu_a,
        const float* __restrict__ w2, const float* __restrict__ b2,
        const float* __restrict__ wc, const float* __restrict__ wp,
        float* __restrict__ ws, int fp16mode) {
    float* acc   = ws + ACC_OFF;   // also covers deg (contiguous 60000)
    float* sarr  = ws + SARR_OFF;
    float* inv   = ws + INV_OFF;
    ushort* nvis = (ushort*)((char*)ws + NV_BYTE_OFF);

    const int t      = threadIdx.x;
    const int gid    = blockIdx.x * blockDim.x + t;
    const int stride = gridDim.x * blockDim.x;
    const int lane   = t & 63;
    const int wave   = gid >> 6;
    const int nwave  = stride >> 6;

    // --- zero acc + deg (slice) ---
    for (int i = gid; i < 2 * N_NODES; i += stride) acc[i] = 0.f;

    // --- block-local full moments of x ---
    __shared__ float red[4][5];
    __shared__ float s_scale[HID], s_shift[HID], s_u[HID], s_w1a[HID], s_w1b[HID];
    __shared__ float s_wpc[HID];
    __shared__ float s_sb;
    {
        float s0 = 0.f, s1 = 0.f, s00 = 0.f, s11 = 0.f, s01 = 0.f;
        for (int i = t; i < N_NODES; i += 256) {
            float2 v = ((const float2*)x)[i];
            s0  += v.x;       s1  += v.y;
            s00 += v.x * v.x; s11 += v.y * v.y;
            s01 += v.x * v.y;
        }
        for (int o = 32; o; o >>= 1) {
            s0  += __shfl_xor(s0,  o, 64);
            s1  += __shfl_xor(s1,  o, 64);
            s00 += __shfl_xor(s00, o, 64);
            s11 += __shfl_xor(s11, o, 64);
            s01 += __shfl_xor(s01, o, 64);
        }
        int wv = t >> 6;
        if (lane == 0) {
            red[wv][0] = s0; red[wv][1] = s1; red[wv][2] = s00;
            red[wv][3] = s11; red[wv][4] = s01;
        }
    }
    __syncthreads();
    if (t < HID) {
        float S0  = red[0][0] + red[1][0] + red[2][0] + red[3][0];
        float S1  = red[0][1] + red[1][1] + red[2][1] + red[3][1];
        float S00 = red[0][2] + red[1][2] + red[2][2] + red[3][2];
        float S11 = red[0][3] + red[1][3] + red[2][3] + red[3][3];
        float S01 = red[0][4] + red[1][4] + red[2][4] + red[3][4];
        float wpck = 0.f;
        for (int j = 0; j < HID; ++j) wpck += wp[j] * wc[j * HID + t];
        s_wpc[t] = wpck;
        const float invN = 1.0f / (float)N_NODES;
        float m0  = S0 * invN, m1 = S1 * invN;
        float v0  = fmaxf(S00 * invN - m0 * m0, 0.f);
        float v1  = fmaxf(S11 * invN - m1 * m1, 0.f);
        float c01 = S01 * invN - m0 * m1;
        float a0 = w1[2 * t], a1 = w1[2 * t + 1];
        float mean = a0 * m0 + a1 * m1 + b1[t];
        float var  = fmaxf(a0 * a0 * v0 + a1 * a1 * v1 + 2.f * a0 * a1 * c01, 0.f);
        float rs    = 1.0f / sqrtf(var + 1e-5f);
        float scale = gamma[t] * rs;
        s_scale[t] = scale;
        s_shift[t] = beta[t] - mean * scale;
        s_w1a[t] = a0; s_w1b[t] = a1;
    }
    __syncthreads();
    if (t < HID) {
        float uu = 0.f;
        for (int k = 0; k < HID; ++k) uu += s_wpc[k] * w2[k * HID + t];
        s_u[t] = uu;
    }
    if (t == 0) {
        float sb = 0.f;
        for (int k = 0; k < HID; ++k) sb += s_wpc[k] * b2[k];
        s_sb = sb;
    }
    __syncthreads();

    // --- sarr slice ---
    {
        const float aslope = prelu_a[0];
        const float sb = s_sb;
        for (int i = gid; i < N_NODES; i += stride) {
            float2 xv = ((const float2*)x)[i];
            float sacc = sb;
            #pragma unroll
            for (int c = 0; c < HID; ++c) {
                float h  = s_w1a[c] * xv.x + s_w1b[c] * xv.y + b1[c];
                float tt = h * s_scale[c] + s_shift[c];
                tt = tt >= 0.f ? tt : aslope * tt;
                sacc += tt * s_u[c];
            }
            sarr[i] = sacc;
        }
    }

    // --- normalize visual rows (wave per node) ---
    for (int node = wave; node < N_NODES; node += nwave) {
        const float4* row = (const float4*)(visual + (size_t)node * VD);
        float4 a = row[lane];
        float4 b = row[lane + 64];
        float p = a.x*a.x + a.y*a.y + a.z*a.z + a.w*a.w
                + b.x*b.x + b.y*b.y + b.z*b.z + b.w*b.w;
        for (int o = 32; o; o >>= 1) p += __shfl_xor(p, o, 64);
        float r = 1.0f / fmaxf(sqrtf(p), 1e-8f);
        if (fp16mode) {
            __half2 p0 = __floats2half2_rn(a.x * r, a.y * r);
            __half2 p1 = __floats2half2_rn(a.z * r, a.w * r);
            __half2 p2 = __floats2half2_rn(b.x * r, b.y * r);
            __half2 p3 = __floats2half2_rn(b.z * r, b.w * r);
            uint2 q0, q1;
            q0.x = *(unsigned int*)&p0; q0.y = *(unsigned int*)&p1;
            q1.x = *(unsigned int*)&p2; q1.y = *(unsigned int*)&p3;
            uint2* orow = (uint2*)(nvis + (size_t)node * VD);
            orow[lane]      = q0;
            orow[lane + 64] = q1;
        } else if (lane == 0) {
            inv[node] = r;
        }
    }
}

// ================= K2: edge kernel (fp16, pre-normalized) =================
__global__ void __launch_bounds__(256) k2_edge16(const int* __restrict__ ei,
                                                 const float* __restrict__ ws_ro,
                                                 float* __restrict__ acc,
                                                 float* __restrict__ deg,
                                                 const float* __restrict__ sarr) {
    const uint4* nvis = (const uint4*)((const char*)ws_ro + NV_BYTE_OFF);
    int wave  = (blockIdx.x * blockDim.x + threadIdx.x) >> 6;
    int lane  = threadIdx.x & 63;
    int nwave = (gridDim.x * blockDim.x) >> 6;
    for (int e = wave; e < E_EDGES; e += nwave) {
        int s = ei[e];
        int d = ei[E_EDGES + e];
        uint4 A = nvis[(size_t)s * 64 + lane];
        uint4 B = nvis[(size_t)d * 64 + lane];
        float2 a0 = h2f(A.x), a1 = h2f(A.y), a2 = h2f(A.z), a3 = h2f(A.w);
        float2 b0 = h2f(B.x), b1 = h2f(B.y), b2 = h2f(B.z), b3 = h2f(B.w);
        float p = a0.x*b0.x + a0.y*b0.y + a1.x*b1.x + a1.y*b1.y
                + a2.x*b2.x + a2.y*b2.y + a3.x*b3.x + a3.y*b3.y;
        for (int o = 32; o; o >>= 1) p += __shfl_xor(p, o, 64);
        if (lane == 0) {
            atomicAdd(&acc[d], p * sarr[s]);
            atomicAdd(&deg[d], 1.0f);
        }
    }
}

// fp32 fallback edge kernel
__global__ void __launch_bounds__(256) k2_edge32(const int* __restrict__ ei,
                                                 const float* __restrict__ visual,
                                                 const float* __restrict__ inv,
                                                 const float* __restrict__ sarr,
                                                 float* __restrict__ acc,
                                                 float* __restrict__ deg) {
    int wave  = (blockIdx.x * blockDim.x + threadIdx.x) >> 6;
    int lane  = threadIdx.x & 63;
    int nwave = (gridDim.x * blockDim.x) >> 6;
    for (int e = wave; e < E_EDGES; e += nwave) {
        int s = ei[e];
        int d = ei[E_EDGES + e];
        const float4* ra = (const float4*)(visual + (size_t)s * VD);
        const float4* rb = (const float4*)(visual + (size_t)d * VD);
        float4 a0 = ra[lane];
        float4 b0 = rb[lane];
        float4 a1 = ra[lane + 64];
        float4 b1 = rb[lane + 64];
        float p = a0.x*b0.x + a0.y*b0.y + a0.z*b0.z + a0.w*b0.w
                + a1.x*b1.x + a1.y*b1.y + a1.z*b1.z + a1.w*b1.w;
        for (int o = 32; o; o >>= 1) p += __shfl_xor(p, o, 64);
        if (lane == 0) {
            float w = p * inv[s] * inv[d];
            atomicAdd(&acc[d], w * sarr[s]);
            atomicAdd(&deg[d], 1.0f);
        }
    }
}

// ================= K3: final =================
__global__ void k3_final(const float* __restrict__ acc, const float* __restrict__ deg,
                         const float* __restrict__ bc, const float* __restrict__ wp,
                         const float* __restrict__ bp, float* __restrict__ out, int n) {
    float K = bp[0];
    #pragma unroll
    for (int j = 0; j < HID; ++j) K += wp[j] * bc[j];
    for (int i = blockIdx.x * blockDim.x + threadIdx.x; i < n; i += gridDim.x * blockDim.x) {
        out[i] = acc[i] / fmaxf(deg[i], 1.0f) + K;
    }
}

extern "C" void kernel_launch(void* const* d_in, const int* in_sizes, int n_in,
                              void* d_out, int out_size, void* d_ws, size_t ws_size,
                              hipStream_t stream) {
    const float* x       = (const float*)d_in[0];
    const float* visual  = (const float*)d_in[1];
    const int*   ei      = (const int*)  d_in[2];
    const float* w1      = (const float*)d_in[3];
    const float* b1      = (const float*)d_in[4];
    const float* gamma   = (const float*)d_in[5];
    const float* beta    = (const float*)d_in[6];
    const float* prelu_a = (const float*)d_in[7];
    const float* w2      = (const float*)d_in[8];
    const float* b2      = (const float*)d_in[9];
    const float* wc      = (const float*)d_in[10];
    const float* bc      = (const float*)d_in[11];
    const float* wp      = (const float*)d_in[12];
    const float* bp      = (const float*)d_in[13];
    float* out = (float*)d_out;

    float* ws   = (float*)d_ws;
    float* acc  = ws + ACC_OFF;
    float* deg  = ws + DEG_OFF;
    float* sarr = ws + SARR_OFF;
    float* inv  = ws + INV_OFF;

    bool fp16ok = ws_size >= (size_t)NV_BYTE_OFF + (size_t)N_NODES * VD * 2;

    k1_node<<<512, 256, 0, stream>>>(x, visual, w1, b1, gamma, beta, prelu_a,
                                     w2, b2, wc, wp, ws, fp16ok ? 1 : 0);
    if (fp16ok) {
        k2_edge16<<<4096, 256, 0, stream>>>(ei, ws, acc, deg, sarr);
    } else {
        k2_edge32<<<4096, 256, 0, stream>>>(ei, visual, inv, sarr, acc, deg);
    }
    k3_final<<<120, 256, 0, stream>>>(acc, deg, bc, wp, bp, out, N_NODES);
}

// Round 7
// 256.627 us; speedup vs baseline: 8.3514x; 1.2952x over previous
//
#include <hip/hip_runtime.h>
#include <hip/hip_fp16.h>
#include <math.h>

#define N_NODES 30000
#define E_EDGES 480000
#define VD      512
#define HID     32
#define NSTATB  120
#define BUCKET  3750   // rows per src-bucket: 3750 * 1KB = 3.75 MB < 4 MB per-XCD L2

// ws layout (float index):
//   [0, 30000)      acc   (zeroed by k_prep16)
//   [30000, 60000)  deg   (zeroed by k_prep16)
//   [60000, 90000)  sarr  (k_node)
//   [90000, 90600)  part  (NSTATB x 5 moment partials, k_statsp)
//   [90624, 120624) inv   (fp32 fallback only)
//   byte 360448+    nvis  (fp16 normalized rows, 1024 B/row, k_prep16)
#define ACC_OFF  0
#define DEG_OFF  30000
#define SARR_OFF 60000
#define PART_OFF 90000
#define INV_OFF  90624
#define NV_BYTE_OFF 360448u

__device__ inline float2 h2f(unsigned int u) {
    const __half2 h = *reinterpret_cast<const __half2*>(&u);
    return __half22float2(h);
}

// ---------------- k_statsp: per-block partial moments of x (R3-proven) ----------------
__global__ void __launch_bounds__(256) k_statsp(const float* __restrict__ x,
                                                float* __restrict__ part, int n) {
    __shared__ float red[4][5];
    float s0 = 0.f, s1 = 0.f, s00 = 0.f, s11 = 0.f, s01 = 0.f;
    for (int i = blockIdx.x * blockDim.x + threadIdx.x; i < n; i += gridDim.x * blockDim.x) {
        float2 v = ((const float2*)x)[i];
        s0  += v.x;       s1  += v.y;
        s00 += v.x * v.x; s11 += v.y * v.y;
        s01 += v.x * v.y;
    }
    for (int o = 32; o; o >>= 1) {
        s0  += __shfl_xor(s0,  o, 64);
        s1  += __shfl_xor(s1,  o, 64);
        s00 += __shfl_xor(s00, o, 64);
        s11 += __shfl_xor(s11, o, 64);
        s01 += __shfl_xor(s01, o, 64);
    }
    int wv = threadIdx.x >> 6;
    if ((threadIdx.x & 63) == 0) {
        red[wv][0] = s0; red[wv][1] = s1; red[wv][2] = s00;
        red[wv][3] = s11; red[wv][4] = s01;
    }
    __syncthreads();
    if (threadIdx.x < 5) {
        part[blockIdx.x * 5 + threadIdx.x] =
            red[0][threadIdx.x] + red[1][threadIdx.x] +
            red[2][threadIdx.x] + red[3][threadIdx.x];
    }
}

// ---------------- k_node: fold stats, per-node scalar s[] (R3-proven) ----------------
__global__ void __launch_bounds__(256) k_node(
        const float* __restrict__ x,
        const float* __restrict__ w1, const float* __restrict__ b1,
        const float* __restrict__ gamma, const float* __restrict__ beta,
        const float* __restrict__ prelu_a,
        const float* __restrict__ w2, const float* __restrict__ b2,
        const float* __restrict__ wc, const float* __restrict__ wp,
        const float* __restrict__ part,
        float* __restrict__ sarr, int n) {
    __shared__ float s_scale[HID], s_shift[HID], s_u[HID], s_w1a[HID], s_w1b[HID];
    __shared__ float s_wpc[HID];
    __shared__ float s_sb;
    int t = threadIdx.x;
    if (t < HID) {
        float S0 = 0, S1 = 0, S00 = 0, S11 = 0, S01 = 0;
        for (int p = 0; p < NSTATB; ++p) {
            S0  += part[p * 5 + 0];
            S1  += part[p * 5 + 1];
            S00 += part[p * 5 + 2];
            S11 += part[p * 5 + 3];
            S01 += part[p * 5 + 4];
        }
        float wpck = 0.f;
        for (int j = 0; j < HID; ++j) wpck += wp[j] * wc[j * HID + t];
        s_wpc[t] = wpck;
        const float invN = 1.0f / (float)n;
        float m0  = S0 * invN, m1 = S1 * invN;
        float v0  = fmaxf(S00 * invN - m0 * m0, 0.f);
        float v1  = fmaxf(S11 * invN - m1 * m1, 0.f);
        float c01 = S01 * invN - m0 * m1;
        float a0 = w1[2 * t], a1 = w1[2 * t + 1];
        float mean = a0 * m0 + a1 * m1 + b1[t];
        float var  = fmaxf(a0 * a0 * v0 + a1 * a1 * v1 + 2.f * a0 * a1 * c01, 0.f);
        float rs    = 1.0f / sqrtf(var + 1e-5f);
        float scale = gamma[t] * rs;
        s_scale[t] = scale;
        s_shift[t] = beta[t] - mean * scale;
        s_w1a[t] = a0; s_w1b[t] = a1;
    }
    __syncthreads();
    if (t < HID) {
        float uu = 0.f;
        for (int k = 0; k < HID; ++k) uu += s_wpc[k] * w2[k * HID + t];
        s_u[t] = uu;
    }
    if (t == 0) {
        float sb = 0.f;
        for (int k = 0; k < HID; ++k) sb += s_wpc[k] * b2[k];
        s_sb = sb;
    }
    __syncthreads();
    const float aslope = prelu_a[0];
    const float sb = s_sb;
    for (int i = blockIdx.x * blockDim.x + t; i < n; i += gridDim.x * blockDim.x) {
        float2 xv = ((const float2*)x)[i];
        float sacc = sb;
        #pragma unroll
        for (int c = 0; c < HID; ++c) {
            float h  = s_w1a[c] * xv.x + s_w1b[c] * xv.y + b1[c];
            float tt = h * s_scale[c] + s_shift[c];
            tt = tt >= 0.f ? tt : aslope * tt;
            sacc += tt * s_u[c];
        }
        sarr[i] = sacc;
    }
}

// ---------------- k_prep16: normalize rows -> fp16, zero acc/deg (R3-proven) ----------------
__global__ void __launch_bounds__(256) k_prep16(const float* __restrict__ visual,
                                                float* __restrict__ ws, int n) {
    int gid = blockIdx.x * blockDim.x + threadIdx.x;
    if (gid < 2 * N_NODES) ws[gid] = 0.f;  // acc + deg
    ushort* nvis = (ushort*)((char*)ws + NV_BYTE_OFF);
    int wave  = gid >> 6;
    int lane  = threadIdx.x & 63;
    int nwave = (gridDim.x * blockDim.x) >> 6;
    for (int node = wave; node < n; node += nwave) {
        const float4* row = (const float4*)(visual + (size_t)node * VD);
        float4 a = row[lane];
        float4 b = row[lane + 64];
        float p = a.x*a.x + a.y*a.y + a.z*a.z + a.w*a.w
                + b.x*b.x + b.y*b.y + b.z*b.z + b.w*b.w;
        for (int o = 32; o; o >>= 1) p += __shfl_xor(p, o, 64);
        float r = 1.0f / fmaxf(sqrtf(p), 1e-8f);
        __half2 p0 = __floats2half2_rn(a.x * r, a.y * r);
        __half2 p1 = __floats2half2_rn(a.z * r, a.w * r);
        __half2 p2 = __floats2half2_rn(b.x * r, b.y * r);
        __half2 p3 = __floats2half2_rn(b.z * r, b.w * r);
        uint2 q0, q1;
        q0.x = *(unsigned int*)&p0; q0.y = *(unsigned int*)&p1;
        q1.x = *(unsigned int*)&p2; q1.y = *(unsigned int*)&p3;
        uint2* orow = (uint2*)(nvis + (size_t)node * VD);
        orow[lane]      = q0;
        orow[lane + 64] = q1;
    }
}

// ---------------- k_edge16p: src-bucketed skip-scan edge kernel ----------------
// Block residue r = blockIdx%8 (round-robin -> XCD r). Each wave stages 64 edges
// lane-parallel, ballots the ones whose src-bucket == r, and processes those
// wave-wide. Per XCD, src gathers fall in a 3.75 MB L2-resident window.
__global__ void __launch_bounds__(256) k_edge16p(const int* __restrict__ ei,
                                                 const float* __restrict__ ws_ro,
                                                 float* __restrict__ acc,
                                                 float* __restrict__ deg,
                                                 const float* __restrict__ sarr) {
    const uint4* nvis = (const uint4*)((const char*)ws_ro + NV_BYTE_OFF);
    const int lane = threadIdx.x & 63;
    const int r    = blockIdx.x & 7;                       // src-bucket residue
    const int q    = (blockIdx.x >> 3) * (blockDim.x >> 6) + (threadIdx.x >> 6);
    const int nq   = (gridDim.x >> 3) * (blockDim.x >> 6); // scan-waves per residue
    const int nchunk = (E_EDGES + 63) >> 6;                // 7500

    for (int c = q; c < nchunk; c += nq) {
        int base = c << 6;
        int idx  = base + lane;
        bool valid = idx < E_EDGES;
        int s = valid ? ei[idx] : 0;
        int d = valid ? ei[E_EDGES + idx] : 0;
        bool mine = valid && (s / BUCKET == r);
        float mys = mine ? sarr[s] : 0.f;
        unsigned long long m = __ballot(mine);
        while (m) {
            int j = __ffsll(m) - 1;
            m &= m - 1;
            int   sj = __shfl(s,   j, 64);
            int   dj = __shfl(d,   j, 64);
            float sv = __shfl(mys, j, 64);
            uint4 A = nvis[(size_t)sj * 64 + lane];
            uint4 B = nvis[(size_t)dj * 64 + lane];
            float2 a0 = h2f(A.x), a1 = h2f(A.y), a2 = h2f(A.z), a3 = h2f(A.w);
            float2 b0 = h2f(B.x), b1 = h2f(B.y), b2 = h2f(B.z), b3 = h2f(B.w);
            float p = a0.x*b0.x + a0.y*b0.y + a1.x*b1.x + a1.y*b1.y
                    + a2.x*b2.x + a2.y*b2.y + a3.x*b3.x + a3.y*b3.y;
            for (int o = 32; o; o >>= 1) p += __shfl_xor(p, o, 64);
            if (lane == 0) {
                atomicAdd(&acc[dj], p * sv);
                atomicAdd(&deg[dj], 1.0f);
            }
        }
    }
}

// ---------------- fp32 fallback path ----------------
__global__ void __launch_bounds__(256) k_prep32(const float* __restrict__ visual,
                                                float* __restrict__ ws, int n) {
    int gid = blockIdx.x * blockDim.x + threadIdx.x;
    if (gid < 2 * N_NODES) ws[gid] = 0.f;
    float* inv = ws + INV_OFF;
    int wave  = gid >> 6;
    int lane  = threadIdx.x & 63;
    int nwave = (gridDim.x * blockDim.x) >> 6;
    for (int node = wave; node < n; node += nwave) {
        const float4* row = (const float4*)(visual + (size_t)node * VD);
        float4 a = row[lane];
        float4 b = row[lane + 64];
        float p = a.x*a.x + a.y*a.y + a.z*a.z + a.w*a.w
                + b.x*b.x + b.y*b.y + b.z*b.z + b.w*b.w;
        for (int o = 32; o; o >>= 1) p += __shfl_xor(p, o, 64);
        if (lane == 0) inv[node] = 1.0f / fmaxf(sqrtf(p), 1e-8f);
    }
}

__global__ void __launch_bounds__(256) k_edge32(const int* __restrict__ ei,
                                                const float* __restrict__ visual,
                                                const float* __restrict__ inv,
                                                const float* __restrict__ sarr,
                                                float* __restrict__ acc,
                                                float* __restrict__ deg) {
    int wave  = (blockIdx.x * blockDim.x + threadIdx.x) >> 6;
    int lane  = threadIdx.x & 63;
    int nwave = (gridDim.x * blockDim.x) >> 6;
    for (int e = wave; e < E_EDGES; e += nwave) {
        int s = ei[e];
        int d = ei[E_EDGES + e];
        const float4* ra = (const float4*)(visual + (size_t)s * VD);
        const float4* rb = (const float4*)(visual + (size_t)d * VD);
        float4 a0 = ra[lane];
        float4 b0 = rb[lane];
        float4 a1 = ra[lane + 64];
        float4 b1 = rb[lane + 64];
        float p = a0.x*b0.x + a0.y*b0.y + a0.z*b0.z + a0.w*b0.w
                + a1.x*b1.x + a1.y*b1.y + a1.z*b1.z + a1.w*b1.w;
        for (int o = 32; o; o >>= 1) p += __shfl_xor(p, o, 64);
        if (lane == 0) {
            float w = p * inv[s] * inv[d];
            atomicAdd(&acc[d], w * sarr[s]);
            atomicAdd(&deg[d], 1.0f);
        }
    }
}

// ---------------- k_final ----------------
__global__ void k_final(const float* __restrict__ acc, const float* __restrict__ deg,
                        const float* __restrict__ bc, const float* __restrict__ wp,
                        const float* __restrict__ bp, float* __restrict__ out, int n) {
    float K = bp[0];
    #pragma unroll
    for (int j = 0; j < HID; ++j) K += wp[j] * bc[j];
    for (int i = blockIdx.x * blockDim.x + threadIdx.x; i < n; i += gridDim.x * blockDim.x) {
        out[i] = acc[i] / fmaxf(deg[i], 1.0f) + K;
    }
}

extern "C" void kernel_launch(void* const* d_in, const int* in_sizes, int n_in,
                              void* d_out, int out_size, void* d_ws, size_t ws_size,
                              hipStream_t stream) {
    const float* x       = (const float*)d_in[0];
    const float* visual  = (const float*)d_in[1];
    const int*   ei      = (const int*)  d_in[2];
    const float* w1      = (const float*)d_in[3];
    const float* b1      = (const float*)d_in[4];
    const float* gamma   = (const float*)d_in[5];
    const float* beta    = (const float*)d_in[6];
    const float* prelu_a = (const float*)d_in[7];
    const float* w2      = (const float*)d_in[8];
    const float* b2      = (const float*)d_in[9];
    const float* wc      = (const float*)d_in[10];
    const float* bc      = (const float*)d_in[11];
    const float* wp      = (const float*)d_in[12];
    const float* bp      = (const float*)d_in[13];
    float* out = (float*)d_out;

    float* ws   = (float*)d_ws;
    float* acc  = ws + ACC_OFF;
    float* deg  = ws + DEG_OFF;
    float* sarr = ws + SARR_OFF;
    float* part = ws + PART_OFF;
    float* inv  = ws + INV_OFF;

    bool fp16ok = ws_size >= (size_t)NV_BYTE_OFF + (size_t)N_NODES * VD * 2;

    k_statsp<<<NSTATB, 256, 0, stream>>>(x, part, N_NODES);
    k_node  <<<256, 256, 0, stream>>>(x, w1, b1, gamma, beta, prelu_a, w2, b2, wc, wp,
                                      part, sarr, N_NODES);
    if (fp16ok) {
        k_prep16 <<<512, 256, 0, stream>>>(visual, ws, N_NODES);
        k_edge16p<<<4096, 256, 0, stream>>>(ei, ws, acc, deg, sarr);
    } else {
        k_prep32<<<512, 256, 0, stream>>>(visual, ws, N_NODES);
        k_edge32<<<4096, 256, 0, stream>>>(ei, visual, inv, sarr, acc, deg);
    }
    k_final<<<120, 256, 0, stream>>>(acc, deg, bc, wp, bp, out, N_NODES);
}